// Round 11
// baseline (233.594 us; speedup 1.0000x reference)
//
#include <hip/hip_runtime.h>
#include <math.h>

// Problem constants
#define NG   12
#define NH   8
#define CIN  64
#define CQK  32
#define CVAL 32
#define COUT 64
#define NB   2
#define NN   512
#define NROWS (NB * NN)     // 1024
#define GHH  (NG * NH)      // 96 heads
#define DIN  (NG * CIN)     // 768
#define DQK  (GHH * CQK)    // 3072
#define DOUT (NG * COUT)    // 768

typedef __attribute__((ext_vector_type(8))) short bf16x8;
typedef __attribute__((ext_vector_type(4))) float f32x4;
typedef unsigned short ushort_t;

#define SZU ((size_t)NROWS * DQK)   // 3145728 elements (ushort count per plane)

// ---------------------------------------------------------------------------
// split fp32 -> (hi, lo) bf16 planes.  x = hi + lo + O(2^-16 x).
// ---------------------------------------------------------------------------
__device__ __forceinline__ ushort_t bf16_rne(float v) {
    unsigned u = __float_as_uint(v);
    return (ushort_t)((u + 0x7fffu + ((u >> 16) & 1u)) >> 16);
}

// ---------------------------------------------------------------------------
// Fused prep (block-range dispatch):
// blocks [0,384):   X split + swizzle into A-frag order Xr[m>>4][kc][m&15][8]
// blocks [384,672): Wq/Wk/Wv split + swizzle into B-frag order
// ---------------------------------------------------------------------------
__global__ __launch_bounds__(256) void prep_kernel(
    const float* __restrict__ feat,
    const float* __restrict__ Wq, const float* __restrict__ Wk,
    const float* __restrict__ Wv,
    ushort_t* __restrict__ Xrh, ushort_t* __restrict__ Xrl,
    ushort_t* __restrict__ Wqh, ushort_t* __restrict__ Wql)
{
    const int bb = blockIdx.x;
    if (bb < 384) {
        const int t  = bb * 256 + threadIdx.x;   // [0, 98304)
        const int mr  = t & 15;
        const int u   = t >> 4;
        const int kc  = u % 96;
        const int m16 = u / 96;
        const float* src = feat + (size_t)(m16 * 16 + mr) * DIN + kc * 8;
        float v[8];
        *(float4*)v       = *(const float4*)src;
        *(float4*)(v + 4) = *(const float4*)(src + 4);
        ushort_t h8[8] __attribute__((aligned(16)));
        ushort_t l8[8] __attribute__((aligned(16)));
        #pragma unroll
        for (int j = 0; j < 8; ++j) {
            ushort_t hb = bf16_rne(v[j]);
            float hf = __uint_as_float(((unsigned)hb) << 16);
            h8[j] = hb;
            l8[j] = bf16_rne(v[j] - hf);
        }
        const size_t dst = ((size_t)m16 * 96 + kc) * 128 + mr * 8;
        *(uint4*)(Xrh + dst) = *(const uint4*)h8;
        *(uint4*)(Xrl + dst) = *(const uint4*)l8;
    } else {
        const int zz = (bb - 384) / 96;
        const float* W = (zz == 0) ? Wq : (zz == 1) ? Wk : Wv;
        ushort_t* hi = Wqh + (size_t)zz * 196608;
        ushort_t* lo = Wql + (size_t)zz * 196608;
        const int t  = ((bb - 384) % 96) * 256 + threadIdx.x;   // [0, 24576)
        const int kc = t & 7;
        const int o  = (t >> 3) & 255;
        const int gp = t >> 11;
        const float* src = W + ((size_t)(gp * 256 + o)) * 64 + kc * 8;
        float v[8];
        *(float4*)v       = *(const float4*)src;
        *(float4*)(v + 4) = *(const float4*)(src + 4);
        ushort_t h8[8] __attribute__((aligned(16)));
        ushort_t l8[8] __attribute__((aligned(16)));
        #pragma unroll
        for (int j = 0; j < 8; ++j) {
            ushort_t hb = bf16_rne(v[j]);
            float hf = __uint_as_float(((unsigned)hb) << 16);
            h8[j] = hb;
            l8[j] = bf16_rne(v[j] - hf);
        }
        const size_t dst = ((size_t)(gp * 16 + (o >> 4)) * 8 + kc) * 128 + (o & 15) * 8;
        *(uint4*)(hi + dst) = *(const uint4*)h8;
        *(uint4*)(lo + dst) = *(const uint4*)l8;
    }
}

// ---------------------------------------------------------------------------
// Wo split + swizzle (runs after attn; lives in the then-dead ao region).
// ---------------------------------------------------------------------------
__global__ __launch_bounds__(256) void wo_swz_kernel(
    const float* __restrict__ Wo, ushort_t* __restrict__ hi,
    ushort_t* __restrict__ lo)
{
    const int t  = blockIdx.x * 256 + threadIdx.x;   // [0, 24576)
    const int kc = t & 31;
    const int o  = (t >> 5) & 63;
    const int gp = t >> 11;
    const float* src = Wo + ((size_t)(gp * 64 + o)) * 256 + kc * 8;
    float v[8];
    *(float4*)v       = *(const float4*)src;
    *(float4*)(v + 4) = *(const float4*)(src + 4);
    ushort_t h8[8] __attribute__((aligned(16)));
    ushort_t l8[8] __attribute__((aligned(16)));
    #pragma unroll
    for (int j = 0; j < 8; ++j) {
        ushort_t hb = bf16_rne(v[j]);
        float hf = __uint_as_float(((unsigned)hb) << 16);
        h8[j] = hb;
        l8[j] = bf16_rne(v[j] - hf);
    }
    const size_t dst = ((size_t)(gp * 4 + (o >> 4)) * 32 + kc) * 128 + (o & 15) * 8;
    *(uint4*)(hi + dst) = *(const uint4*)h8;
    *(uint4*)(lo + dst) = *(const uint4*)l8;
}

// ---------------------------------------------------------------------------
// Kernel 1: block-circulant QKV projection, split-bf16 MFMA, NO LDS/barriers.
// z=0 -> q fp32; z=1 -> K fp32 (consumed by norm_rope); z=2 -> split-bf16
// V^T written directly in B-fragment order Vr[b][gh][vt][key>>3][vd&15][key&7].
// ---------------------------------------------------------------------------
__global__ __launch_bounds__(256, 1) void qkv_mfma_kernel(
    const ushort_t* __restrict__ Xrh, const ushort_t* __restrict__ Xrl,
    const ushort_t* __restrict__ Wrh, const ushort_t* __restrict__ Wrl,
    float* __restrict__ qo, float* __restrict__ ko,
    ushort_t* __restrict__ vrh, ushort_t* __restrict__ vrl)
{
    const int z = blockIdx.z;
    const ushort_t* Wh = Wrh + (size_t)z * 196608;
    const ushort_t* Wl = Wrl + (size_t)z * 196608;
    const int m0 = blockIdx.y * 128;
    const int c0 = blockIdx.x * 128;
    const int hg = c0 >> 8;
    const int o0 = c0 & 255;
    const int tid  = threadIdx.x;
    const int lane = tid & 63;
    const int w    = tid >> 6;
    const int wm   = (w >> 1) * 64;
    const int wn   = (w & 1) * 64;
    const int lm   = lane & 15;
    const int lq   = lane >> 4;
    const int tA0  = (m0 + wm) >> 4;
    const int ct0  = (o0 + wn) >> 4;

    f32x4 acc[4][4];
    #pragma unroll
    for (int i = 0; i < 4; ++i)
        #pragma unroll
        for (int j = 0; j < 4; ++j) acc[i][j] = (f32x4)(0.0f);

    for (int ks = 0; ks < 24; ++ks) {
        const int g = ks >> 1;
        int gp = g - hg; if (gp < 0) gp += NG;
        bf16x8 ah[4], al[4], bh[4], bl[4];
        #pragma unroll
        for (int mt = 0; mt < 4; ++mt) {
            const size_t aoff = ((size_t)(tA0 + mt) * 96 + ks * 4 + lq) * 128 + lm * 8;
            ah[mt] = *(const bf16x8*)(Xrh + aoff);
            al[mt] = *(const bf16x8*)(Xrl + aoff);
        }
        const size_t bbase = ((size_t)(gp * 16 + ct0) * 8 + (ks & 1) * 4 + lq) * 128 + lm * 8;
        #pragma unroll
        for (int nt = 0; nt < 4; ++nt) {
            bh[nt] = *(const bf16x8*)(Wh + bbase + nt * 1024);
            bl[nt] = *(const bf16x8*)(Wl + bbase + nt * 1024);
        }
        #pragma unroll
        for (int mt = 0; mt < 4; ++mt)
            #pragma unroll
            for (int nt = 0; nt < 4; ++nt) {
                acc[mt][nt] = __builtin_amdgcn_mfma_f32_16x16x32_bf16(ah[mt], bh[nt], acc[mt][nt], 0, 0, 0);
                acc[mt][nt] = __builtin_amdgcn_mfma_f32_16x16x32_bf16(ah[mt], bl[nt], acc[mt][nt], 0, 0, 0);
                acc[mt][nt] = __builtin_amdgcn_mfma_f32_16x16x32_bf16(al[mt], bh[nt], acc[mt][nt], 0, 0, 0);
            }
    }
    if (z < 2) {
        float* __restrict__ out = (z == 0) ? qo : ko;
        #pragma unroll
        for (int mt = 0; mt < 4; ++mt)
            #pragma unroll
            for (int r = 0; r < 4; ++r) {
                float* dst = out + (size_t)(m0 + wm + mt * 16 + lq * 4 + r) * DQK + c0 + wn + lm;
                #pragma unroll
                for (int nt = 0; nt < 4; ++nt) dst[nt * 16] = acc[mt][nt][r];
            }
    } else {
        // split-bf16 V^T fragment scatter
        #pragma unroll
        for (int mt = 0; mt < 4; ++mt)
            #pragma unroll
            for (int r = 0; r < 4; ++r) {
                const int m = m0 + wm + mt * 16 + lq * 4 + r;
                const int bidx = m >> 9, key = m & 511;
                #pragma unroll
                for (int nt = 0; nt < 4; ++nt) {
                    const int col = c0 + wn + nt * 16 + lm;
                    const int gh2 = col >> 5, vd = col & 31;
                    const size_t addr = ((((size_t)(bidx * GHH + gh2) * 2 + (vd >> 4)) * 64
                                          + (key >> 3)) * 16 + (vd & 15)) * 8 + (key & 7);
                    const float x = acc[mt][nt][r];
                    const ushort_t hb = bf16_rne(x);
                    vrh[addr] = hb;
                    vrl[addr] = bf16_rne(x - __uint_as_float(((unsigned)hb) << 16));
                }
            }
    }
}

// ---------------------------------------------------------------------------
// Kernel 2: RMSNorm + fused ropes. q written back fp32 in-place; K written
// as split-bf16 B-fragment planes Kr[b][gh][n>>4][kc][n&15][8].
// ---------------------------------------------------------------------------
__global__ __launch_bounds__(256) void norm_rope_kernel(
    float* __restrict__ q, const float* __restrict__ kin,
    ushort_t* __restrict__ krh, ushort_t* __restrict__ krl,
    const float* __restrict__ coords,
    const int* __restrict__ seq,
    const float* __restrict__ qw,
    const float* __restrict__ kw,
    const float* __restrict__ pf)
{
    const int hid = blockIdx.x * 256 + threadIdx.x;
    const int gh = hid % GHH;
    const int bn = hid / GHH;
    const int g = gh >> 3;
    const int h = gh & 7;
    float* qp = q + (size_t)hid * CQK;
    const float* kp = kin + (size_t)hid * CQK;
    float xq[CQK], xk[CQK];
    #pragma unroll
    for (int u = 0; u < 8; ++u) *(float4*)(xq + 4 * u) = *(const float4*)(qp + 4 * u);
    #pragma unroll
    for (int u = 0; u < 8; ++u) *(float4*)(xk + 4 * u) = *(const float4*)(kp + 4 * u);

    float sq = 0.f, sk = 0.f;
    #pragma unroll
    for (int c = 0; c < CQK; ++c) { sq = fmaf(xq[c], xq[c], sq); sk = fmaf(xk[c], xk[c], sk); }
    const float eps = 1.1920928955078125e-07f;
    const float invq = rsqrtf(sq * (1.f / CQK) + eps);
    const float invk = rsqrtf(sk * (1.f / CQK) + eps);
    #pragma unroll
    for (int c = 0; c < CQK; ++c) { xq[c] *= invq * qw[c]; xk[c] *= invk * kw[c]; }

    const float pos = (float)seq[bn];
    const float cx = coords[bn * 3 + 0], cy = coords[bn * 3 + 1], cz = coords[bn * 3 + 2];
    float sg, cg;
    sincosf((float)g * 0.5235987755982988f, &sg, &cg);
    const float u0 = cg * cx + sg * cy;
    const float u1 = cg * cy - sg * cx;
    const float u2 = cz;

    #pragma unroll
    for (int f = 0; f < 16; ++f) {
        const float invf = exp2f(-(float)f * 0.8304820237218405f);
        const float* fr = pf + ((size_t)h * 16 + f) * 3;
        const float ang = fmaf(pos, invf, u0 * fr[0] + u1 * fr[1] + u2 * fr[2]);
        float sn, cs;
        sincosf(ang, &sn, &cs);
        float a1 = xq[2 * f], a2 = xq[2 * f + 1];
        xq[2 * f]     = a1 * cs - a2 * sn;
        xq[2 * f + 1] = a1 * sn + a2 * cs;
        float b1 = xk[2 * f], b2 = xk[2 * f + 1];
        xk[2 * f]     = b1 * cs - b2 * sn;
        xk[2 * f + 1] = b1 * sn + b2 * cs;
    }
    #pragma unroll
    for (int u = 0; u < 8; ++u) *(float4*)(qp + 4 * u) = *(const float4*)(xq + 4 * u);

    // K -> split-bf16 B-fragment planes
    const int b = bn >> 9, n = bn & 511;
    const size_t kbase = (((size_t)(b * GHH + gh) * 32 + (n >> 4)) * 4) * 128 + (n & 15) * 8;
    #pragma unroll
    for (int kc = 0; kc < 4; ++kc) {
        ushort_t h8[8] __attribute__((aligned(16)));
        ushort_t l8[8] __attribute__((aligned(16)));
        #pragma unroll
        for (int j = 0; j < 8; ++j) {
            const float x = xk[kc * 8 + j];
            const ushort_t hb = bf16_rne(x);
            h8[j] = hb;
            l8[j] = bf16_rne(x - __uint_as_float(((unsigned)hb) << 16));
        }
        *(uint4*)(krh + kbase + kc * 128) = *(const uint4*)h8;
        *(uint4*)(krl + kbase + kc * 128) = *(const uint4*)l8;
    }
}

// ---------------------------------------------------------------------------
// Kernel 3 (RESTRUCTURED): MFMA flash attention, ZERO barriers, no K/V LDS.
// K/V fragments stream from pre-split global planes (coalesced 1 KB reads).
// LDS = Ps only (18.4 KB, wave-private rows). K-tile 64.
// Epilogue writes AO split planes in A-fragment order.
// ---------------------------------------------------------------------------
__global__ __launch_bounds__(256, 1) void attn_mfma_kernel(
    const float* __restrict__ q,
    const ushort_t* __restrict__ krh, const ushort_t* __restrict__ krl,
    const ushort_t* __restrict__ vrh, const ushort_t* __restrict__ vrl,
    ushort_t* __restrict__ aoh,     // A-frag order [m>>4][384][16][8]
    ushort_t* __restrict__ aol)
{
    __shared__ __attribute__((aligned(16))) ushort_t Ps[128][72];

    const int gh    = blockIdx.x;
    const int chunk = blockIdx.y;
    const int b     = blockIdx.z;
    const size_t headoff = (size_t)b * NN * DQK + (size_t)gh * CQK;
    const size_t khead = (size_t)(b * GHH + gh) * 16384;
    const size_t vhead = (size_t)(b * GHH + gh) * 16384;
    const int tid  = threadIdx.x;
    const int lane = tid & 63;
    const int w    = tid >> 6;
    const int lm   = lane & 15;
    const int lq   = lane >> 4;       // quad
    const int qloc = w * 32;          // wave's local q-row base (0..96)

    const float scale = 0.17677669529663687f;  // 1/sqrt(32)
    bf16x8 qh[2], ql[2];
    #pragma unroll
    for (int mt = 0; mt < 2; ++mt) {
        const int row = chunk * 128 + qloc + mt * 16 + lm;
        const float* qp = q + headoff + (size_t)row * DQK + lq * 8;
        float4 t0 = *(const float4*)qp;
        float4 t1 = *(const float4*)(qp + 4);
        float vals[8] = {t0.x, t0.y, t0.z, t0.w, t1.x, t1.y, t1.z, t1.w};
        short h8[8], l8[8];
        #pragma unroll
        for (int j = 0; j < 8; ++j) {
            float x = vals[j] * scale;
            ushort_t hb = bf16_rne(x);
            float hf = __uint_as_float(((unsigned)hb) << 16);
            h8[j] = (short)hb;
            l8[j] = (short)bf16_rne(x - hf);
        }
        qh[mt] = *(bf16x8*)h8;
        ql[mt] = *(bf16x8*)l8;
    }

    float mrun[2][4], lrun[2][4];
    f32x4 o[2][2];
    #pragma unroll
    for (int mt = 0; mt < 2; ++mt) {
        #pragma unroll
        for (int r = 0; r < 4; ++r) { mrun[mt][r] = -3.0e38f; lrun[mt][r] = 0.f; }
        o[mt][0] = (f32x4)(0.0f); o[mt][1] = (f32x4)(0.0f);
    }

    for (int j0 = 0; j0 < NN; j0 += 64) {
        // ---- S = Q K^T for 64 keys (4 n-tiles), K frags from global ----
        f32x4 sf[2][4];
        #pragma unroll
        for (int nt = 0; nt < 4; ++nt) {
            const size_t kb = khead + ((size_t)(((j0 >> 4) + nt) * 4 + lq)) * 128 + lm * 8;
            bf16x8 bh = *(const bf16x8*)(krh + kb);
            bf16x8 bl = *(const bf16x8*)(krl + kb);
            #pragma unroll
            for (int mt = 0; mt < 2; ++mt) {
                f32x4 s = (f32x4)(0.0f);
                s = __builtin_amdgcn_mfma_f32_16x16x32_bf16(qh[mt], bh, s, 0, 0, 0);
                s = __builtin_amdgcn_mfma_f32_16x16x32_bf16(qh[mt], bl, s, 0, 0, 0);
                s = __builtin_amdgcn_mfma_f32_16x16x32_bf16(ql[mt], bh, s, 0, 0, 0);
                sf[mt][nt] = s;
            }
        }

        // ---- online softmax; P (bf16) -> LDS (wave-private rows) ----
        #pragma unroll
        for (int mt = 0; mt < 2; ++mt) {
            float cr[4];
            #pragma unroll
            for (int r = 0; r < 4; ++r) {
                float t = sf[mt][0][r];
                #pragma unroll
                for (int nt = 1; nt < 4; ++nt) t = fmaxf(t, sf[mt][nt][r]);
                t = fmaxf(t, __shfl_xor(t, 1, 64));
                t = fmaxf(t, __shfl_xor(t, 2, 64));
                t = fmaxf(t, __shfl_xor(t, 4, 64));
                t = fmaxf(t, __shfl_xor(t, 8, 64));
                const float mn = fmaxf(mrun[mt][r], t);
                cr[r] = __expf(mrun[mt][r] - mn);
                mrun[mt][r] = mn;
                lrun[mt][r] *= cr[r];
            }
            o[mt][0] *= f32x4{cr[0], cr[1], cr[2], cr[3]};
            o[mt][1] *= f32x4{cr[0], cr[1], cr[2], cr[3]};
            float rsum[4] = {0.f, 0.f, 0.f, 0.f};
            #pragma unroll
            for (int nt = 0; nt < 4; ++nt) {
                #pragma unroll
                for (int r = 0; r < 4; ++r) {
                    const float p = __expf(sf[mt][nt][r] - mrun[mt][r]);
                    rsum[r] += p;
                    Ps[qloc + mt * 16 + lq * 4 + r][nt * 16 + lm] = bf16_rne(p);
                }
            }
            #pragma unroll
            for (int r = 0; r < 4; ++r) {
                float t = rsum[r];
                t += __shfl_xor(t, 1, 64);
                t += __shfl_xor(t, 2, 64);
                t += __shfl_xor(t, 4, 64);
                t += __shfl_xor(t, 8, 64);
                lrun[mt][r] += t;
            }
        }

        // ---- O += P V (V frags from global; Ps wave-private, no barrier) ----
        #pragma unroll
        for (int kt = 0; kt < 2; ++kt) {
            bf16x8 pa[2];
            #pragma unroll
            for (int mt = 0; mt < 2; ++mt)
                pa[mt] = *(const bf16x8*)&Ps[qloc + mt * 16 + lm][kt * 32 + lq * 8];
            #pragma unroll
            for (int vt = 0; vt < 2; ++vt) {
                const size_t vb = vhead + ((size_t)(vt * 64 + (j0 >> 3) + kt * 4 + lq) * 16 + lm) * 8;
                bf16x8 bvh = *(const bf16x8*)(vrh + vb);
                bf16x8 bvl = *(const bf16x8*)(vrl + vb);
                #pragma unroll
                for (int mt = 0; mt < 2; ++mt) {
                    o[mt][vt] = __builtin_amdgcn_mfma_f32_16x16x32_bf16(pa[mt], bvh, o[mt][vt], 0, 0, 0);
                    o[mt][vt] = __builtin_amdgcn_mfma_f32_16x16x32_bf16(pa[mt], bvl, o[mt][vt], 0, 0, 0);
                }
            }
        }
    }

    // ---- epilogue: normalize + split-bf16 store in A-FRAGMENT order ----
    const int mtbase = (b * 512 + chunk * 128 + qloc) >> 4;
    const int kc0 = gh * 4 + (lm >> 3);
    const int j0w = lm & 7;
    #pragma unroll
    for (int mt = 0; mt < 2; ++mt) {
        float inv[4];
        #pragma unroll
        for (int r = 0; r < 4; ++r) inv[r] = 1.f / lrun[mt][r];
        #pragma unroll
        for (int r = 0; r < 4; ++r) {
            const size_t base = ((size_t)(mtbase + mt) * 384 + kc0) * 128 + (lq * 4 + r) * 8 + j0w;
            const float x0 = o[mt][0][r] * inv[r];
            const float x1 = o[mt][1][r] * inv[r];
            const ushort_t h0 = bf16_rne(x0);
            const ushort_t h1 = bf16_rne(x1);
            aoh[base]       = h0;
            aoh[base + 256] = h1;   // +2 kc
            aol[base]       = bf16_rne(x0 - __uint_as_float(((unsigned)h0) << 16));
            aol[base + 256] = bf16_rne(x1 - __uint_as_float(((unsigned)h1) << 16));
        }
    }
}

// ---------------------------------------------------------------------------
// Kernel 4: output projection, split-bf16 MFMA, split-K=8, NO LDS/barriers.
// ---------------------------------------------------------------------------
__global__ __launch_bounds__(256, 1) void oproj_mfma_kernel(
    const ushort_t* __restrict__ Arh, const ushort_t* __restrict__ Arl,
    const ushort_t* __restrict__ Worh, const ushort_t* __restrict__ Worl,
    float* __restrict__ part)                                 // [8][1024][768]
{
    const int h  = blockIdx.x;
    const int m0 = blockIdx.y * 128;
    const int kz = blockIdx.z;
    const int tid  = threadIdx.x;
    const int lane = tid & 63;
    const int w    = tid >> 6;
    const int wm   = (w >> 1) * 64;
    const int wn   = (w & 1) * 32;
    const int lm   = lane & 15;
    const int lq   = lane >> 4;
    const int tA0  = (m0 + wm) >> 4;
    const int ctb  = wn >> 4;               // 0 or 2

    f32x4 acc[4][2];
    #pragma unroll
    for (int i = 0; i < 4; ++i) { acc[i][0] = (f32x4)(0.0f); acc[i][1] = (f32x4)(0.0f); }

    for (int ks = 0; ks < 12; ++ks) {
        const int k0 = kz * 384 + ks * 32;
        const int g  = k0 >> 8;
        int gp = g - h; if (gp < 0) gp += NG;
        const int kcA = kz * 48 + ks * 4 + lq;
        const int kcB = ((k0 & 255) >> 3) + lq;
        bf16x8 ah[4], al[4], bh[2], bl[2];
        #pragma unroll
        for (int mt = 0; mt < 4; ++mt) {
            const size_t aoff = ((size_t)(tA0 + mt) * 384 + kcA) * 128 + lm * 8;
            ah[mt] = *(const bf16x8*)(Arh + aoff);
            al[mt] = *(const bf16x8*)(Arl + aoff);
        }
        const size_t bbase = ((size_t)(gp * 4 + ctb) * 32 + kcB) * 128 + lm * 8;
        #pragma unroll
        for (int nt = 0; nt < 2; ++nt) {
            bh[nt] = *(const bf16x8*)(Worh + bbase + nt * 4096);
            bl[nt] = *(const bf16x8*)(Worl + bbase + nt * 4096);
        }
        #pragma unroll
        for (int mt = 0; mt < 4; ++mt)
            #pragma unroll
            for (int nt = 0; nt < 2; ++nt) {
                acc[mt][nt] = __builtin_amdgcn_mfma_f32_16x16x32_bf16(ah[mt], bh[nt], acc[mt][nt], 0, 0, 0);
                acc[mt][nt] = __builtin_amdgcn_mfma_f32_16x16x32_bf16(ah[mt], bl[nt], acc[mt][nt], 0, 0, 0);
                acc[mt][nt] = __builtin_amdgcn_mfma_f32_16x16x32_bf16(al[mt], bh[nt], acc[mt][nt], 0, 0, 0);
            }
    }
    float* dst0 = part + (size_t)kz * (NROWS * DOUT);
    #pragma unroll
    for (int mt = 0; mt < 4; ++mt)
        #pragma unroll
        for (int r = 0; r < 4; ++r) {
            float* dst = dst0 + (size_t)(m0 + wm + mt * 16 + lq * 4 + r) * DOUT + h * 64 + wn + lm;
            dst[0]  = acc[mt][0][r];
            dst[16] = acc[mt][1][r];
        }
}

__global__ __launch_bounds__(256) void reduce8_kernel(
    const float* __restrict__ part, float* __restrict__ out)
{
    const int i = blockIdx.x * 256 + threadIdx.x;   // over 196608 float4s
    const float4* p = (const float4*)part;
    const int s = NROWS * DOUT / 4;                 // 196608
    float4 r = p[i];
    #pragma unroll
    for (int j = 1; j < 8; ++j) {
        float4 t = p[i + j * s];
        r.x += t.x; r.y += t.y; r.z += t.z; r.w += t.w;
    }
    ((float4*)out)[i] = r;
}

// ---------------------------------------------------------------------------
extern "C" void kernel_launch(void* const* d_in, const int* in_sizes, int n_in,
                              void* d_out, int out_size, void* d_ws, size_t ws_size,
                              hipStream_t stream)
{
    const float* feat   = (const float*)d_in[0];
    const float* coords = (const float*)d_in[1];
    const float* Wq     = (const float*)d_in[2];
    const float* Wk     = (const float*)d_in[3];
    const float* Wv     = (const float*)d_in[4];
    const float* Wo     = (const float*)d_in[5];
    const float* qw     = (const float*)d_in[6];
    const float* kw     = (const float*)d_in[7];
    const float* pf     = (const float*)d_in[8];
    const int*   seq    = (const int*)d_in[9];

    // regions (each SZU floats): q | k(->Vr planes) | v(->K fp32, later AOr) | ao(->Xr/W, later Kr, later WOr)
    float* qreg  = (float*)d_ws;
    float* kreg  = qreg + SZU;
    float* vreg  = kreg + SZU;
    float* aoreg = vreg + SZU;

    ushort_t* Xrh = (ushort_t*)aoreg;
    ushort_t* Xrl = Xrh + (size_t)NROWS * DIN;               // 786432 each
    ushort_t* Wqh = Xrl + (size_t)NROWS * DIN;
    ushort_t* Wql = Wqh + (size_t)3 * 196608;

    ushort_t* Vrh = (ushort_t*)kreg;
    ushort_t* Vrl = Vrh + SZU;
    float*    Kfp = vreg;
    ushort_t* Krh = (ushort_t*)aoreg;     // after qkv (Xr/W dead)
    ushort_t* Krl = Krh + SZU;
    ushort_t* AOrh = (ushort_t*)vreg;     // after norm_rope (K fp32 dead)
    ushort_t* AOrl = AOrh + SZU;
    ushort_t* WOrh = (ushort_t*)aoreg;    // after attn (Kr dead)
    ushort_t* WOrl = WOrh + (size_t)196608;
    float*    part = (float*)d_ws;        // 8 x 786432 floats (q+k regions, dead after attn)

    prep_kernel<<<dim3(672), 256, 0, stream>>>(feat, Wq, Wk, Wv, Xrh, Xrl, Wqh, Wql);
    qkv_mfma_kernel<<<dim3(24, 8, 3), 256, 0, stream>>>(Xrh, Xrl, Wqh, Wql, qreg, Kfp, Vrh, Vrl);
    norm_rope_kernel<<<dim3(384), 256, 0, stream>>>(qreg, Kfp, Krh, Krl, coords, seq, qw, kw, pf);
    attn_mfma_kernel<<<dim3(96, 4, 2), 256, 0, stream>>>(qreg, Krh, Krl, Vrh, Vrl, AOrh, AOrl);

    wo_swz_kernel<<<dim3(96), 256, 0, stream>>>(Wo, WOrh, WOrl);
    oproj_mfma_kernel<<<dim3(12, 8, 8), 256, 0, stream>>>(AOrh, AOrl, WOrh, WOrl, part);
    reduce8_kernel<<<dim3(768), 256, 0, stream>>>(part, (float*)d_out);
}

// Round 12
// 208.847 us; speedup vs baseline: 1.1185x; 1.1185x over previous
//
#include <hip/hip_runtime.h>
#include <math.h>

// Problem constants
#define NG   12
#define NH   8
#define CIN  64
#define CQK  32
#define CVAL 32
#define COUT 64
#define NB   2
#define NN   512
#define NROWS (NB * NN)     // 1024
#define GHH  (NG * NH)      // 96 heads
#define DIN  (NG * CIN)     // 768
#define DQK  (GHH * CQK)    // 3072
#define DOUT (NG * COUT)    // 768

typedef __attribute__((ext_vector_type(8))) short bf16x8;
typedef __attribute__((ext_vector_type(4))) float f32x4;
typedef unsigned short ushort_t;

#define SZU ((size_t)NROWS * DQK)   // 3145728 elements per fp32 region

// ---------------------------------------------------------------------------
// split fp32 -> (hi, lo) bf16 planes.  x = hi + lo + O(2^-16 x).
// ---------------------------------------------------------------------------
__device__ __forceinline__ ushort_t bf16_rne(float v) {
    unsigned u = __float_as_uint(v);
    return (ushort_t)((u + 0x7fffu + ((u >> 16) & 1u)) >> 16);
}

// ---------------------------------------------------------------------------
// Fused prep (block-range dispatch):
// blocks [0,384):   X split + swizzle into A-frag order Xr[m>>4][kc][m&15][8]
// blocks [384,672): Wq/Wk/Wv split + swizzle into B-frag order
// ---------------------------------------------------------------------------
__global__ __launch_bounds__(256) void prep_kernel(
    const float* __restrict__ feat,
    const float* __restrict__ Wq, const float* __restrict__ Wk,
    const float* __restrict__ Wv,
    ushort_t* __restrict__ Xrh, ushort_t* __restrict__ Xrl,
    ushort_t* __restrict__ Wqh, ushort_t* __restrict__ Wql)
{
    const int bb = blockIdx.x;
    if (bb < 384) {
        const int t  = bb * 256 + threadIdx.x;   // [0, 98304)
        const int mr  = t & 15;
        const int u   = t >> 4;
        const int kc  = u % 96;
        const int m16 = u / 96;
        const float* src = feat + (size_t)(m16 * 16 + mr) * DIN + kc * 8;
        float v[8];
        *(float4*)v       = *(const float4*)src;
        *(float4*)(v + 4) = *(const float4*)(src + 4);
        ushort_t h8[8] __attribute__((aligned(16)));
        ushort_t l8[8] __attribute__((aligned(16)));
        #pragma unroll
        for (int j = 0; j < 8; ++j) {
            ushort_t hb = bf16_rne(v[j]);
            float hf = __uint_as_float(((unsigned)hb) << 16);
            h8[j] = hb;
            l8[j] = bf16_rne(v[j] - hf);
        }
        const size_t dst = ((size_t)m16 * 96 + kc) * 128 + mr * 8;
        *(uint4*)(Xrh + dst) = *(const uint4*)h8;
        *(uint4*)(Xrl + dst) = *(const uint4*)l8;
    } else {
        const int zz = (bb - 384) / 96;
        const float* W = (zz == 0) ? Wq : (zz == 1) ? Wk : Wv;
        ushort_t* hi = Wqh + (size_t)zz * 196608;
        ushort_t* lo = Wql + (size_t)zz * 196608;
        const int t  = ((bb - 384) % 96) * 256 + threadIdx.x;   // [0, 24576)
        const int kc = t & 7;
        const int o  = (t >> 3) & 255;
        const int gp = t >> 11;
        const float* src = W + ((size_t)(gp * 256 + o)) * 64 + kc * 8;
        float v[8];
        *(float4*)v       = *(const float4*)src;
        *(float4*)(v + 4) = *(const float4*)(src + 4);
        ushort_t h8[8] __attribute__((aligned(16)));
        ushort_t l8[8] __attribute__((aligned(16)));
        #pragma unroll
        for (int j = 0; j < 8; ++j) {
            ushort_t hb = bf16_rne(v[j]);
            float hf = __uint_as_float(((unsigned)hb) << 16);
            h8[j] = hb;
            l8[j] = bf16_rne(v[j] - hf);
        }
        const size_t dst = ((size_t)(gp * 16 + (o >> 4)) * 8 + kc) * 128 + (o & 15) * 8;
        *(uint4*)(hi + dst) = *(const uint4*)h8;
        *(uint4*)(lo + dst) = *(const uint4*)l8;
    }
}

// ---------------------------------------------------------------------------
// Wo split + swizzle (after attn; lives in the then-dead Kr region).
// ---------------------------------------------------------------------------
__global__ __launch_bounds__(256) void wo_swz_kernel(
    const float* __restrict__ Wo, ushort_t* __restrict__ hi,
    ushort_t* __restrict__ lo)
{
    const int t  = blockIdx.x * 256 + threadIdx.x;   // [0, 24576)
    const int kc = t & 31;
    const int o  = (t >> 5) & 63;
    const int gp = t >> 11;
    const float* src = Wo + ((size_t)(gp * 64 + o)) * 256 + kc * 8;
    float v[8];
    *(float4*)v       = *(const float4*)src;
    *(float4*)(v + 4) = *(const float4*)(src + 4);
    ushort_t h8[8] __attribute__((aligned(16)));
    ushort_t l8[8] __attribute__((aligned(16)));
    #pragma unroll
    for (int j = 0; j < 8; ++j) {
        ushort_t hb = bf16_rne(v[j]);
        float hf = __uint_as_float(((unsigned)hb) << 16);
        h8[j] = hb;
        l8[j] = bf16_rne(v[j] - hf);
    }
    const size_t dst = ((size_t)(gp * 4 + (o >> 4)) * 32 + kc) * 128 + (o & 15) * 8;
    *(uint4*)(hi + dst) = *(const uint4*)h8;
    *(uint4*)(lo + dst) = *(const uint4*)l8;
}

// ---------------------------------------------------------------------------
// Kernel 1: block-circulant QKV projection, split-bf16 MFMA, NO LDS/barriers.
// All three outputs fp32 (clean coalesced stores — round-9 proven version).
// ---------------------------------------------------------------------------
__global__ __launch_bounds__(256, 1) void qkv_mfma_kernel(
    const ushort_t* __restrict__ Xrh, const ushort_t* __restrict__ Xrl,
    const ushort_t* __restrict__ Wrh, const ushort_t* __restrict__ Wrl,
    float* __restrict__ qo, float* __restrict__ ko, float* __restrict__ vo)
{
    const int z = blockIdx.z;
    float* __restrict__ out = (z == 0) ? qo : (z == 1) ? ko : vo;
    const ushort_t* Wh = Wrh + (size_t)z * 196608;
    const ushort_t* Wl = Wrl + (size_t)z * 196608;
    const int m0 = blockIdx.y * 128;
    const int c0 = blockIdx.x * 128;
    const int hg = c0 >> 8;
    const int o0 = c0 & 255;
    const int tid  = threadIdx.x;
    const int lane = tid & 63;
    const int w    = tid >> 6;
    const int wm   = (w >> 1) * 64;
    const int wn   = (w & 1) * 64;
    const int lm   = lane & 15;
    const int lq   = lane >> 4;
    const int tA0  = (m0 + wm) >> 4;
    const int ct0  = (o0 + wn) >> 4;

    f32x4 acc[4][4];
    #pragma unroll
    for (int i = 0; i < 4; ++i)
        #pragma unroll
        for (int j = 0; j < 4; ++j) acc[i][j] = (f32x4)(0.0f);

    for (int ks = 0; ks < 24; ++ks) {
        const int g = ks >> 1;
        int gp = g - hg; if (gp < 0) gp += NG;
        bf16x8 ah[4], al[4], bh[4], bl[4];
        #pragma unroll
        for (int mt = 0; mt < 4; ++mt) {
            const size_t aoff = ((size_t)(tA0 + mt) * 96 + ks * 4 + lq) * 128 + lm * 8;
            ah[mt] = *(const bf16x8*)(Xrh + aoff);
            al[mt] = *(const bf16x8*)(Xrl + aoff);
        }
        const size_t bbase = ((size_t)(gp * 16 + ct0) * 8 + (ks & 1) * 4 + lq) * 128 + lm * 8;
        #pragma unroll
        for (int nt = 0; nt < 4; ++nt) {
            bh[nt] = *(const bf16x8*)(Wh + bbase + nt * 1024);
            bl[nt] = *(const bf16x8*)(Wl + bbase + nt * 1024);
        }
        #pragma unroll
        for (int mt = 0; mt < 4; ++mt)
            #pragma unroll
            for (int nt = 0; nt < 4; ++nt) {
                acc[mt][nt] = __builtin_amdgcn_mfma_f32_16x16x32_bf16(ah[mt], bh[nt], acc[mt][nt], 0, 0, 0);
                acc[mt][nt] = __builtin_amdgcn_mfma_f32_16x16x32_bf16(ah[mt], bl[nt], acc[mt][nt], 0, 0, 0);
                acc[mt][nt] = __builtin_amdgcn_mfma_f32_16x16x32_bf16(al[mt], bh[nt], acc[mt][nt], 0, 0, 0);
            }
    }
    #pragma unroll
    for (int mt = 0; mt < 4; ++mt)
        #pragma unroll
        for (int r = 0; r < 4; ++r) {
            float* dst = out + (size_t)(m0 + wm + mt * 16 + lq * 4 + r) * DQK + c0 + wn + lm;
            #pragma unroll
            for (int nt = 0; nt < 4; ++nt) dst[nt * 16] = acc[mt][nt][r];
        }
}

// ---------------------------------------------------------------------------
// Kernel 2: RMSNorm + fused ropes. q fp32 in-place; K as split-bf16
// B-fragment planes Kr[b][gh][n>>4][kc][n&15][8] (uint4 coalesced writes).
// ---------------------------------------------------------------------------
__global__ __launch_bounds__(256) void norm_rope_kernel(
    float* __restrict__ q, const float* __restrict__ kin,
    ushort_t* __restrict__ krh, ushort_t* __restrict__ krl,
    const float* __restrict__ coords,
    const int* __restrict__ seq,
    const float* __restrict__ qw,
    const float* __restrict__ kw,
    const float* __restrict__ pf)
{
    const int hid = blockIdx.x * 256 + threadIdx.x;
    const int gh = hid % GHH;
    const int bn = hid / GHH;
    const int g = gh >> 3;
    const int h = gh & 7;
    float* qp = q + (size_t)hid * CQK;
    const float* kp = kin + (size_t)hid * CQK;
    float xq[CQK], xk[CQK];
    #pragma unroll
    for (int u = 0; u < 8; ++u) *(float4*)(xq + 4 * u) = *(const float4*)(qp + 4 * u);
    #pragma unroll
    for (int u = 0; u < 8; ++u) *(float4*)(xk + 4 * u) = *(const float4*)(kp + 4 * u);

    float sq = 0.f, sk = 0.f;
    #pragma unroll
    for (int c = 0; c < CQK; ++c) { sq = fmaf(xq[c], xq[c], sq); sk = fmaf(xk[c], xk[c], sk); }
    const float eps = 1.1920928955078125e-07f;
    const float invq = rsqrtf(sq * (1.f / CQK) + eps);
    const float invk = rsqrtf(sk * (1.f / CQK) + eps);
    #pragma unroll
    for (int c = 0; c < CQK; ++c) { xq[c] *= invq * qw[c]; xk[c] *= invk * kw[c]; }

    const float pos = (float)seq[bn];
    const float cx = coords[bn * 3 + 0], cy = coords[bn * 3 + 1], cz = coords[bn * 3 + 2];
    float sg, cg;
    sincosf((float)g * 0.5235987755982988f, &sg, &cg);
    const float u0 = cg * cx + sg * cy;
    const float u1 = cg * cy - sg * cx;
    const float u2 = cz;

    #pragma unroll
    for (int f = 0; f < 16; ++f) {
        const float invf = exp2f(-(float)f * 0.8304820237218405f);
        const float* fr = pf + ((size_t)h * 16 + f) * 3;
        const float ang = fmaf(pos, invf, u0 * fr[0] + u1 * fr[1] + u2 * fr[2]);
        float sn, cs;
        sincosf(ang, &sn, &cs);
        float a1 = xq[2 * f], a2 = xq[2 * f + 1];
        xq[2 * f]     = a1 * cs - a2 * sn;
        xq[2 * f + 1] = a1 * sn + a2 * cs;
        float b1 = xk[2 * f], b2 = xk[2 * f + 1];
        xk[2 * f]     = b1 * cs - b2 * sn;
        xk[2 * f + 1] = b1 * sn + b2 * cs;
    }
    #pragma unroll
    for (int u = 0; u < 8; ++u) *(float4*)(qp + 4 * u) = *(const float4*)(xq + 4 * u);

    const int b = bn >> 9, n = bn & 511;
    const size_t kbase = (((size_t)(b * GHH + gh) * 32 + (n >> 4)) * 4) * 128 + (n & 15) * 8;
    #pragma unroll
    for (int kc = 0; kc < 4; ++kc) {
        ushort_t h8[8] __attribute__((aligned(16)));
        ushort_t l8[8] __attribute__((aligned(16)));
        #pragma unroll
        for (int j = 0; j < 8; ++j) {
            const float x = xk[kc * 8 + j];
            const ushort_t hb = bf16_rne(x);
            h8[j] = hb;
            l8[j] = bf16_rne(x - __uint_as_float(((unsigned)hb) << 16));
        }
        *(uint4*)(krh + kbase + kc * 128) = *(const uint4*)h8;
        *(uint4*)(krl + kbase + kc * 128) = *(const uint4*)l8;
    }
}

// ---------------------------------------------------------------------------
// Kernel 2b: V pack — fp32 V -> split-bf16 V^T B-fragment planes.
// Vr[b*96+gh][vd>>4][key>>3][vd&15][key&7]; reads AND writes coalesced by
// construction (thread = (b,gh,kc,vd); per-j reads are 128B runs, per-thread
// writes are uint4 in a 256B run across 16 lanes). No LDS.
// ---------------------------------------------------------------------------
__global__ __launch_bounds__(256) void vpack_kernel(
    const float* __restrict__ v,
    ushort_t* __restrict__ vrh, ushort_t* __restrict__ vrl)
{
    const int t  = blockIdx.x * 256 + threadIdx.x;   // [0, 393216)
    const int vd = t & 31;
    const int kc = (t >> 5) & 63;
    const int bg = t >> 11;                          // [0, 192)
    const int b  = (bg >= GHH) ? 1 : 0;
    const int gh = bg - b * GHH;
    const float* src = v + (size_t)(b * 512 + kc * 8) * DQK + gh * 32 + vd;
    ushort_t h8[8] __attribute__((aligned(16)));
    ushort_t l8[8] __attribute__((aligned(16)));
    #pragma unroll
    for (int j = 0; j < 8; ++j) {
        const float x = src[j * DQK];
        const ushort_t hb = bf16_rne(x);
        h8[j] = hb;
        l8[j] = bf16_rne(x - __uint_as_float(((unsigned)hb) << 16));
    }
    const size_t dst = ((size_t)(bg * 2 + (vd >> 4)) * 64 + kc) * 128 + (vd & 15) * 8;
    *(uint4*)(vrh + dst) = *(const uint4*)h8;
    *(uint4*)(vrl + dst) = *(const uint4*)l8;
}

// ---------------------------------------------------------------------------
// Kernel 3: MFMA flash attention, NO-MAX softmax.
// RMSNorm bounds |s| <= sqrt(32) (rope is a rotation), so exp(s) <= 287:
// no running max, no rescale, no per-iter shfls. Per-lane row-sum partials;
// single 4-deep shfl reduce at the end. K/V frags stream from global planes;
// LDS = Ps only (wave-private rows -> zero barriers).
// ---------------------------------------------------------------------------
__global__ __launch_bounds__(256, 1) void attn_mfma_kernel(
    const float* __restrict__ q,
    const ushort_t* __restrict__ krh, const ushort_t* __restrict__ krl,
    const ushort_t* __restrict__ vrh, const ushort_t* __restrict__ vrl,
    ushort_t* __restrict__ aoh,     // A-frag order [m>>4][384][16][8]
    ushort_t* __restrict__ aol)
{
    __shared__ __attribute__((aligned(16))) ushort_t Ps[128][72];

    const int gh    = blockIdx.x;
    const int chunk = blockIdx.y;
    const int b     = blockIdx.z;
    const size_t headoff = (size_t)b * NN * DQK + (size_t)gh * CQK;
    const size_t kvhead = (size_t)(b * GHH + gh) * 16384;
    const int tid  = threadIdx.x;
    const int lane = tid & 63;
    const int w    = tid >> 6;
    const int lm   = lane & 15;
    const int lq   = lane >> 4;       // quad
    const int qloc = w * 32;          // wave's local q-row base (0..96)

    const float scale = 0.17677669529663687f;  // 1/sqrt(32)
    bf16x8 qh[2], ql[2];
    #pragma unroll
    for (int mt = 0; mt < 2; ++mt) {
        const int row = chunk * 128 + qloc + mt * 16 + lm;
        const float* qp = q + headoff + (size_t)row * DQK + lq * 8;
        float4 t0 = *(const float4*)qp;
        float4 t1 = *(const float4*)(qp + 4);
        float vals[8] = {t0.x, t0.y, t0.z, t0.w, t1.x, t1.y, t1.z, t1.w};
        short h8[8], l8[8];
        #pragma unroll
        for (int j = 0; j < 8; ++j) {
            float x = vals[j] * scale;
            ushort_t hb = bf16_rne(x);
            float hf = __uint_as_float(((unsigned)hb) << 16);
            h8[j] = (short)hb;
            l8[j] = (short)bf16_rne(x - hf);
        }
        qh[mt] = *(bf16x8*)h8;
        ql[mt] = *(bf16x8*)l8;
    }

    float lacc[2][4];
    f32x4 o[2][2];
    #pragma unroll
    for (int mt = 0; mt < 2; ++mt) {
        #pragma unroll
        for (int r = 0; r < 4; ++r) lacc[mt][r] = 0.f;
        o[mt][0] = (f32x4)(0.0f); o[mt][1] = (f32x4)(0.0f);
    }

    for (int j0 = 0; j0 < NN; j0 += 64) {
        // ---- S = Q K^T for 64 keys (4 n-tiles), K frags from global ----
        f32x4 sf[2][4];
        #pragma unroll
        for (int nt = 0; nt < 4; ++nt) {
            const size_t kb = kvhead + ((size_t)(((j0 >> 4) + nt) * 4 + lq)) * 128 + lm * 8;
            bf16x8 bh = *(const bf16x8*)(krh + kb);
            bf16x8 bl = *(const bf16x8*)(krl + kb);
            #pragma unroll
            for (int mt = 0; mt < 2; ++mt) {
                f32x4 s = (f32x4)(0.0f);
                s = __builtin_amdgcn_mfma_f32_16x16x32_bf16(qh[mt], bh, s, 0, 0, 0);
                s = __builtin_amdgcn_mfma_f32_16x16x32_bf16(qh[mt], bl, s, 0, 0, 0);
                s = __builtin_amdgcn_mfma_f32_16x16x32_bf16(ql[mt], bh, s, 0, 0, 0);
                sf[mt][nt] = s;
            }
        }

        // ---- p = exp(s); per-lane row-sum; P (bf16) -> wave-private LDS ----
        #pragma unroll
        for (int mt = 0; mt < 2; ++mt)
            #pragma unroll
            for (int nt = 0; nt < 4; ++nt)
                #pragma unroll
                for (int r = 0; r < 4; ++r) {
                    const float p = __expf(sf[mt][nt][r]);
                    lacc[mt][r] += p;
                    Ps[qloc + mt * 16 + lq * 4 + r][nt * 16 + lm] = bf16_rne(p);
                }

        // ---- O += P V (no barrier: Ps rows wave-private) ----
        #pragma unroll
        for (int kt = 0; kt < 2; ++kt) {
            bf16x8 pa[2];
            #pragma unroll
            for (int mt = 0; mt < 2; ++mt)
                pa[mt] = *(const bf16x8*)&Ps[qloc + mt * 16 + lm][kt * 32 + lq * 8];
            #pragma unroll
            for (int vt = 0; vt < 2; ++vt) {
                const size_t vb = kvhead + ((size_t)(vt * 64 + (j0 >> 3) + kt * 4 + lq) * 16 + lm) * 8;
                bf16x8 bvh = *(const bf16x8*)(vrh + vb);
                bf16x8 bvl = *(const bf16x8*)(vrl + vb);
                #pragma unroll
                for (int mt = 0; mt < 2; ++mt) {
                    o[mt][vt] = __builtin_amdgcn_mfma_f32_16x16x32_bf16(pa[mt], bvh, o[mt][vt], 0, 0, 0);
                    o[mt][vt] = __builtin_amdgcn_mfma_f32_16x16x32_bf16(pa[mt], bvl, o[mt][vt], 0, 0, 0);
                }
            }
        }
    }

    // ---- single end-of-kernel l reduction over the 16 col-lanes ----
    #pragma unroll
    for (int mt = 0; mt < 2; ++mt)
        #pragma unroll
        for (int r = 0; r < 4; ++r) {
            float t = lacc[mt][r];
            t += __shfl_xor(t, 1, 64);
            t += __shfl_xor(t, 2, 64);
            t += __shfl_xor(t, 4, 64);
            t += __shfl_xor(t, 8, 64);
            lacc[mt][r] = 1.f / t;
        }

    // ---- epilogue: normalize + split-bf16 store in A-FRAGMENT order ----
    const int mtbase = (b * 512 + chunk * 128 + qloc) >> 4;
    const int kc0 = gh * 4 + (lm >> 3);
    const int j0w = lm & 7;
    #pragma unroll
    for (int mt = 0; mt < 2; ++mt)
        #pragma unroll
        for (int r = 0; r < 4; ++r) {
            const size_t base = ((size_t)(mtbase + mt) * 384 + kc0) * 128 + (lq * 4 + r) * 8 + j0w;
            const float x0 = o[mt][0][r] * lacc[mt][r];
            const float x1 = o[mt][1][r] * lacc[mt][r];
            const ushort_t h0 = bf16_rne(x0);
            const ushort_t h1 = bf16_rne(x1);
            aoh[base]       = h0;
            aoh[base + 256] = h1;   // +2 kc
            aol[base]       = bf16_rne(x0 - __uint_as_float(((unsigned)h0) << 16));
            aol[base + 256] = bf16_rne(x1 - __uint_as_float(((unsigned)h1) << 16));
        }
}

// ---------------------------------------------------------------------------
// Kernel 4: output projection, split-bf16 MFMA, split-K=8, NO LDS/barriers.
// ---------------------------------------------------------------------------
__global__ __launch_bounds__(256, 1) void oproj_mfma_kernel(
    const ushort_t* __restrict__ Arh, const ushort_t* __restrict__ Arl,
    const ushort_t* __restrict__ Worh, const ushort_t* __restrict__ Worl,
    float* __restrict__ part)                                 // [8][1024][768]
{
    const int h  = blockIdx.x;
    const int m0 = blockIdx.y * 128;
    const int kz = blockIdx.z;
    const int tid  = threadIdx.x;
    const int lane = tid & 63;
    const int w    = tid >> 6;
    const int wm   = (w >> 1) * 64;
    const int wn   = (w & 1) * 32;
    const int lm   = lane & 15;
    const int lq   = lane >> 4;
    const int tA0  = (m0 + wm) >> 4;
    const int ctb  = wn >> 4;               // 0 or 2

    f32x4 acc[4][2];
    #pragma unroll
    for (int i = 0; i < 4; ++i) { acc[i][0] = (f32x4)(0.0f); acc[i][1] = (f32x4)(0.0f); }

    for (int ks = 0; ks < 12; ++ks) {
        const int k0 = kz * 384 + ks * 32;
        const int g  = k0 >> 8;
        int gp = g - h; if (gp < 0) gp += NG;
        const int kcA = kz * 48 + ks * 4 + lq;
        const int kcB = ((k0 & 255) >> 3) + lq;
        bf16x8 ah[4], al[4], bh[2], bl[2];
        #pragma unroll
        for (int mt = 0; mt < 4; ++mt) {
            const size_t aoff = ((size_t)(tA0 + mt) * 384 + kcA) * 128 + lm * 8;
            ah[mt] = *(const bf16x8*)(Arh + aoff);
            al[mt] = *(const bf16x8*)(Arl + aoff);
        }
        const size_t bbase = ((size_t)(gp * 4 + ctb) * 32 + kcB) * 128 + lm * 8;
        #pragma unroll
        for (int nt = 0; nt < 2; ++nt) {
            bh[nt] = *(const bf16x8*)(Worh + bbase + nt * 4096);
            bl[nt] = *(const bf16x8*)(Worl + bbase + nt * 4096);
        }
        #pragma unroll
        for (int mt = 0; mt < 4; ++mt)
            #pragma unroll
            for (int nt = 0; nt < 2; ++nt) {
                acc[mt][nt] = __builtin_amdgcn_mfma_f32_16x16x32_bf16(ah[mt], bh[nt], acc[mt][nt], 0, 0, 0);
                acc[mt][nt] = __builtin_amdgcn_mfma_f32_16x16x32_bf16(ah[mt], bl[nt], acc[mt][nt], 0, 0, 0);
                acc[mt][nt] = __builtin_amdgcn_mfma_f32_16x16x32_bf16(al[mt], bh[nt], acc[mt][nt], 0, 0, 0);
            }
    }
    float* dst0 = part + (size_t)kz * (NROWS * DOUT);
    #pragma unroll
    for (int mt = 0; mt < 4; ++mt)
        #pragma unroll
        for (int r = 0; r < 4; ++r) {
            float* dst = dst0 + (size_t)(m0 + wm + mt * 16 + lq * 4 + r) * DOUT + h * 64 + wn + lm;
            dst[0]  = acc[mt][0][r];
            dst[16] = acc[mt][1][r];
        }
}

__global__ __launch_bounds__(256) void reduce8_kernel(
    const float* __restrict__ part, float* __restrict__ out)
{
    const int i = blockIdx.x * 256 + threadIdx.x;   // over 196608 float4s
    const float4* p = (const float4*)part;
    const int s = NROWS * DOUT / 4;                 // 196608
    float4 r = p[i];
    #pragma unroll
    for (int j = 1; j < 8; ++j) {
        float4 t = p[i + j * s];
        r.x += t.x; r.y += t.y; r.z += t.z; r.w += t.w;
    }
    ((float4*)out)[i] = r;
}

// ---------------------------------------------------------------------------
extern "C" void kernel_launch(void* const* d_in, const int* in_sizes, int n_in,
                              void* d_out, int out_size, void* d_ws, size_t ws_size,
                              hipStream_t stream)
{
    const float* feat   = (const float*)d_in[0];
    const float* coords = (const float*)d_in[1];
    const float* Wq     = (const float*)d_in[2];
    const float* Wk     = (const float*)d_in[3];
    const float* Wv     = (const float*)d_in[4];
    const float* Wo     = (const float*)d_in[5];
    const float* qw     = (const float*)d_in[6];
    const float* kw     = (const float*)d_in[7];
    const float* pf     = (const float*)d_in[8];
    const int*   seq    = (const int*)d_in[9];

    // regions (SZU floats each): qreg | kreg | vreg | aoreg
    float* qreg  = (float*)d_ws;
    float* kreg  = qreg + SZU;
    float* vreg  = kreg + SZU;
    float* aoreg = vreg + SZU;

    // phase 1: Xr + Wqkv planes in aoreg (dead until attn output)
    ushort_t* Xrh = (ushort_t*)aoreg;
    ushort_t* Xrl = Xrh + (size_t)NROWS * DIN;               // 786432 each
    ushort_t* Wqh = Xrl + (size_t)NROWS * DIN;
    ushort_t* Wql = Wqh + (size_t)3 * 196608;
    // phase 2: qkv -> q,k,v fp32 in qreg,kreg,vreg.
    // norm_rope: q in place; Kr planes -> aoreg (Xr/W dead).
    ushort_t* Krh = (ushort_t*)aoreg;
    ushort_t* Krl = Krh + SZU;
    // vpack: Vr planes -> kreg (k fp32 dead after norm_rope).
    ushort_t* Vrh = (ushort_t*)kreg;
    ushort_t* Vrl = Vrh + SZU;
    // attn: AOr planes -> vreg (v fp32 dead after vpack).
    ushort_t* AOrh = (ushort_t*)vreg;
    ushort_t* AOrl = AOrh + SZU;
    // after attn: WOr -> aoreg (Kr dead); partials -> qreg+kreg (24 MB, contiguous).
    ushort_t* WOrh = (ushort_t*)aoreg;
    ushort_t* WOrl = WOrh + (size_t)196608;
    float*    part = (float*)d_ws;

    prep_kernel<<<dim3(672), 256, 0, stream>>>(feat, Wq, Wk, Wv, Xrh, Xrl, Wqh, Wql);
    qkv_mfma_kernel<<<dim3(24, 8, 3), 256, 0, stream>>>(Xrh, Xrl, Wqh, Wql, qreg, kreg, vreg);
    norm_rope_kernel<<<dim3(384), 256, 0, stream>>>(qreg, kreg, Krh, Krl, coords, seq, qw, kw, pf);
    vpack_kernel<<<dim3(1536), 256, 0, stream>>>(vreg, Vrh, Vrl);
    attn_mfma_kernel<<<dim3(96, 4, 2), 256, 0, stream>>>(qreg, Krh, Krl, Vrh, Vrl, AOrh, AOrl);

    wo_swz_kernel<<<dim3(96), 256, 0, stream>>>(Wo, WOrh, WOrl);
    oproj_mfma_kernel<<<dim3(12, 8, 8), 256, 0, stream>>>(AOrh, AOrl, WOrh, WOrl, part);
    reduce8_kernel<<<dim3(768), 256, 0, stream>>>(part, (float*)d_out);
}